// Round 1
// baseline (2342.076 us; speedup 1.0000x reference)
//
#include <hip/hip_runtime.h>
#include <cstdint>
#include <cstddef>

#define T_S 64

typedef __attribute__((ext_vector_type(4))) float f32x4;
typedef __attribute__((ext_vector_type(8))) short bh8;

__device__ __forceinline__ unsigned short f2b(float f) {
  uint32_t x = __builtin_bit_cast(uint32_t, f);
  uint32_t r = (x + 0x7FFFu + ((x >> 16) & 1u)) >> 16;
  return (unsigned short)r;
}
__device__ __forceinline__ float b2f(unsigned short u) {
  uint32_t v = ((uint32_t)u) << 16;
  return __builtin_bit_cast(float, v);
}

// ---- one-time: W^T[j][k] bf16, j in [0,4096) over {Wx,Wh,Wattn} rows k in [0,3072)
__global__ __launch_bounds__(256) void k_prep_w(
    const float* __restrict__ Wx, const float* __restrict__ Wh,
    const float* __restrict__ Wa, unsigned short* __restrict__ WT) {
  __shared__ float tile[64][65];
  int j0 = blockIdx.x * 64;
  int k0 = blockIdx.y * 64;
  const float* src; int kk0;
  if (k0 < 1024)      { src = Wx; kk0 = k0; }
  else if (k0 < 2048) { src = Wh; kk0 = k0 - 1024; }
  else                { src = Wa; kk0 = k0 - 2048; }
  for (int i = threadIdx.x; i < 4096; i += 256) {
    int r = i >> 6, c = i & 63;     // r: k-offset, c: j-offset (coalesced read)
    tile[r][c] = src[(size_t)(kk0 + r) * 4096 + (j0 + c)];
  }
  __syncthreads();
  for (int i = threadIdx.x; i < 4096; i += 256) {
    int r = i >> 6, c = i & 63;     // r: j-offset, c: k-offset (coalesced write)
    WT[(size_t)(j0 + r) * 3072 + (k0 + c)] = f2b(tile[c][r]);
  }
}

// ---- one-time: x f32 -> bf16
__global__ void k_conv_x(const float* __restrict__ x, unsigned short* __restrict__ xb) {
  int i = blockIdx.x * blockDim.x + threadIdx.x;
  int stride = gridDim.x * blockDim.x;
  for (; i < 4194304; i += stride) {          // 16.78M elems / 4
    float4 v = ((const float4*)x)[i];
    ushort4 o;
    o.x = f2b(v.x); o.y = f2b(v.y); o.z = f2b(v.z); o.w = f2b(v.w);
    ((ushort4*)xb)[i] = o;
  }
}

// ---- one-time: h0 = c0 = mean(A, last 16)
__global__ __launch_bounds__(256) void k_init(
    const float* __restrict__ A, unsigned short* __restrict__ hb,
    float* __restrict__ cst) {
  int idx = blockIdx.x * 256 + threadIdx.x;   // [0, 262144)
  const float4* a4 = (const float4*)(A + (size_t)idx * 16);
  float s = 0.f;
  #pragma unroll
  for (int q = 0; q < 4; ++q) { float4 v = a4[q]; s += v.x + v.y + v.z + v.w; }
  s *= 0.0625f;
  cst[idx] = s;
  hb[idx] = f2b(s);
}

// ---- per step: attention over 16 spatial positions (one block per batch n)
__global__ __launch_bounds__(256) void k_attn(
    const float* __restrict__ A, const unsigned short* __restrict__ hb,
    unsigned short* __restrict__ attnb) {
  int n = blockIdx.x;
  int tid = threadIdx.x;
  int lane = tid & 63, wave = tid >> 6;
  float areg[4][16];
  float s[16];
  #pragma unroll
  for (int p = 0; p < 16; ++p) s[p] = 0.f;
  #pragma unroll
  for (int r = 0; r < 4; ++r) {
    int h = r * 256 + tid;
    size_t base = (size_t)n * 1024 + h;
    const float4* a4 = (const float4*)(A + base * 16);
    #pragma unroll
    for (int q = 0; q < 4; ++q) {
      float4 v = a4[q];
      areg[r][q*4+0] = v.x; areg[r][q*4+1] = v.y;
      areg[r][q*4+2] = v.z; areg[r][q*4+3] = v.w;
    }
    float hv = b2f(hb[base]);
    #pragma unroll
    for (int p = 0; p < 16; ++p) s[p] += hv * areg[r][p];
  }
  #pragma unroll
  for (int p = 0; p < 16; ++p) {
    float v = s[p];
    #pragma unroll
    for (int off = 32; off > 0; off >>= 1) v += __shfl_xor(v, off);
    s[p] = v;
  }
  __shared__ float red[4][16];
  __shared__ float sc_sh[16];
  if (lane == 0) {
    #pragma unroll
    for (int p = 0; p < 16; ++p) red[wave][p] = s[p];
  }
  __syncthreads();
  if (tid < 16) {
    sc_sh[tid] = (red[0][tid] + red[1][tid] + red[2][tid] + red[3][tid]) * 0.03125f;
  }
  __syncthreads();
  float sc[16];
  #pragma unroll
  for (int p = 0; p < 16; ++p) sc[p] = sc_sh[p];
  float m = sc[0];
  #pragma unroll
  for (int p = 1; p < 16; ++p) m = fmaxf(m, sc[p]);
  float e[16]; float sum = 0.f;
  #pragma unroll
  for (int p = 0; p < 16; ++p) { e[p] = __expf(sc[p] - m); sum += e[p]; }
  float inv = 1.0f / sum;
  #pragma unroll
  for (int r = 0; r < 4; ++r) {
    float a = 0.f;
    #pragma unroll
    for (int p = 0; p < 16; ++p) a += areg[r][p] * e[p];
    attnb[(size_t)n * 1024 + r * 256 + tid] = f2b(a * inv);
  }
}

// ---- per step: a = [xt|h|attn]@[Wx;Wh;Wattn] + b, fused LSTM cell + output write
// grid (64 gate-col tiles of 16, 4 batch tiles of 64), 512 threads = 8 waves
__global__ __launch_bounds__(512) void k_step(
    const unsigned short* __restrict__ xb,
    const unsigned short* __restrict__ WT,
    const float* __restrict__ bias,
    const unsigned short* __restrict__ hr,
    const unsigned short* __restrict__ atb,
    unsigned short* __restrict__ hw,
    float* __restrict__ cst,
    float* __restrict__ out,
    int t)
{
  __shared__ __align__(16) unsigned short smem[18432]; // 2 bufs x (A 64x72 + B 64x72) bf16
  int tid = threadIdx.x;
  int bn = blockIdx.x;   // gate-col tile: cols j0..j0+15 in each of 4 gate quadrants
  int bm = blockIdx.y;   // batch tile of 64
  int lane = tid & 63;
  int wave = tid >> 6;   // 0..7
  int wr = wave >> 1;    // 16-row group
  int wc = wave & 1;     // 32-col group
  int nbase = bm * 64;
  int j0 = bn * 16;

  // staging: each thread 8 bf16 (16B) of A-tile and of B-tile per K-iter
  int srow = tid >> 3;          // 0..63
  int scol = (tid & 7) * 8;
  int bj = ((srow >> 4) * 1024) + j0 + (srow & 15);   // actual weight column
  const unsigned short* bsrc = WT + (size_t)bj * 3072 + scol;

  f32x4 acc0 = {0.f, 0.f, 0.f, 0.f};
  f32x4 acc1 = {0.f, 0.f, 0.f, 0.f};

  uint4 ra, rb;
  auto gload = [&](int kt) {
    int k0 = kt * 64;
    const unsigned short* src; size_t rs; int kloc;
    if (k0 < 1024)      { src = xb + (size_t)t * 1024; rs = (size_t)T_S * 1024; kloc = k0; }
    else if (k0 < 2048) { src = hr;  rs = 1024; kloc = k0 - 1024; }
    else                { src = atb; rs = 1024; kloc = k0 - 2048; }
    ra = *(const uint4*)(src + (size_t)(nbase + srow) * rs + kloc + scol);
    rb = *(const uint4*)(bsrc + k0);
  };

  int frow = lane & 15;
  int fk = (lane >> 4) * 8;

  gload(0);
  int cur = 0;
  for (int kt = 0; kt < 48; ++kt) {
    unsigned short* As = smem + cur * 4608;
    unsigned short* Bs = smem + 9216 + cur * 4608;
    *(uint4*)(As + srow * 72 + scol) = ra;
    *(uint4*)(Bs + srow * 72 + scol) = rb;
    __syncthreads();                 // single barrier/iter: dbuf makes it sufficient
    if (kt + 1 < 48) gload(kt + 1);  // prefetch next tile under compute
    #pragma unroll
    for (int kk = 0; kk < 2; ++kk) {
      bh8 af  = *(const bh8*)(As + (wr * 16 + frow) * 72 + kk * 32 + fk);
      bh8 bf0 = *(const bh8*)(Bs + (wc * 32 + frow) * 72 + kk * 32 + fk);
      bh8 bf1 = *(const bh8*)(Bs + (wc * 32 + 16 + frow) * 72 + kk * 32 + fk);
      acc0 = __builtin_amdgcn_mfma_f32_16x16x32_bf16(af, bf0, acc0, 0, 0, 0);
      acc1 = __builtin_amdgcn_mfma_f32_16x16x32_bf16(af, bf1, acc1, 0, 0, 0);
    }
    cur ^= 1;
  }
  __syncthreads();
  float* a_lds = (float*)smem;   // [64][65] f32 (aliases staging buffers)
  {
    int r0 = wr * 16 + (lane >> 4) * 4;
    int c0 = wc * 32 + frow;
    #pragma unroll
    for (int reg = 0; reg < 4; ++reg) {
      a_lds[(r0 + reg) * 65 + c0]      = acc0[reg];
      a_lds[(r0 + reg) * 65 + c0 + 16] = acc1[reg];
    }
  }
  __syncthreads();
  // fused gates: cols within tile are 4 strips of 16 (i,f,o,g)
  #pragma unroll
  for (int r = 0; r < 2; ++r) {
    int pi = r * 512 + tid;          // 0..1023 = 64 rows x 16 gate cols
    int row = pi >> 4, gl = pi & 15;
    int n = nbase + row;
    int g = j0 + gl;
    float ii = a_lds[row * 65 + gl]      + bias[g];
    float ff = a_lds[row * 65 + 16 + gl] + bias[1024 + g];
    float oo = a_lds[row * 65 + 32 + gl] + bias[2048 + g];
    float gg = a_lds[row * 65 + 48 + gl] + bias[3072 + g];
    size_t ci = (size_t)n * 1024 + g;
    float cold = cst[ci];
    float si = 1.0f / (1.0f + __expf(-ii));
    float sf = 1.0f / (1.0f + __expf(-ff));
    float so = 1.0f / (1.0f + __expf(-oo));
    float tg = 2.0f / (1.0f + __expf(-2.0f * gg)) - 1.0f;
    float cn = sf * cold + si * tg;
    float hn = so * (2.0f / (1.0f + __expf(-2.0f * cn)) - 1.0f);
    cst[ci] = cn;
    out[((size_t)n * T_S + t) * 1024 + g] = hn;
    hw[ci] = f2b(hn);
  }
}

extern "C" void kernel_launch(void* const* d_in, const int* in_sizes, int n_in,
                              void* d_out, int out_size, void* d_ws, size_t ws_size,
                              hipStream_t stream) {
  const float* x  = (const float*)d_in[0];
  const float* A  = (const float*)d_in[1];
  const float* Wx = (const float*)d_in[2];
  const float* Wh = (const float*)d_in[3];
  const float* Wa = (const float*)d_in[4];
  const float* b  = (const float*)d_in[5];
  float* out = (float*)d_out;

  char* ws = (char*)d_ws;
  unsigned short* WT  = (unsigned short*)(ws);              // 25,165,824 B  W^T bf16
  unsigned short* xb  = (unsigned short*)(ws + 25165824);   // 33,554,432 B  x bf16
  unsigned short* hA  = (unsigned short*)(ws + 58720256);   //    524,288 B  h ping
  unsigned short* hB  = (unsigned short*)(ws + 59244544);   //    524,288 B  h pong
  unsigned short* atb = (unsigned short*)(ws + 59768832);   //    524,288 B  attn bf16
  float* cst          = (float*)(ws + 60293120);            //  1,048,576 B  c f32
  if (ws_size < 61341696u) return;  // need ~58.5 MiB scratch

  k_prep_w<<<dim3(64, 48), 256, 0, stream>>>(Wx, Wh, Wa, WT);
  k_conv_x<<<2048, 256, 0, stream>>>(x, xb);
  k_init<<<1024, 256, 0, stream>>>(A, hA, cst);
  for (int t = 0; t < 64; ++t) {
    const unsigned short* hr = (t & 1) ? hB : hA;   // h_{t-1}
    unsigned short* hwv      = (t & 1) ? hA : hB;   // h_t (double-buffered: other
                                                    // blocks may still be reading hr)
    k_attn<<<256, 256, 0, stream>>>(A, hr, atb);
    k_step<<<dim3(64, 4), 512, 0, stream>>>(xb, WT, b, hr, atb, hwv, cst, out, t);
  }
}

// Round 2
// 1931.453 us; speedup vs baseline: 1.2126x; 1.2126x over previous
//
#include <hip/hip_runtime.h>
#include <cstdint>
#include <cstddef>

#define T_S 64

typedef __attribute__((ext_vector_type(4))) float f32x4;
typedef __attribute__((ext_vector_type(8))) short bh8;

__device__ __forceinline__ unsigned short f2b(float f) {
  uint32_t x = __builtin_bit_cast(uint32_t, f);
  uint32_t r = (x + 0x7FFFu + ((x >> 16) & 1u)) >> 16;
  return (unsigned short)r;
}
__device__ __forceinline__ float b2f(unsigned short u) {
  uint32_t v = ((uint32_t)u) << 16;
  return __builtin_bit_cast(float, v);
}

// ======================= shared prep =======================

// h0 = c0 = mean(A, last 16)
__global__ __launch_bounds__(256) void k_init(
    const float* __restrict__ A, unsigned short* __restrict__ hb,
    float* __restrict__ cst) {
  int idx = blockIdx.x * 256 + threadIdx.x;   // [0, 262144)
  const float4* a4 = (const float4*)(A + (size_t)idx * 16);
  float s = 0.f;
  #pragma unroll
  for (int q = 0; q < 4; ++q) { float4 v = a4[q]; s += v.x + v.y + v.z + v.w; }
  s *= 0.0625f;
  cst[idx] = s;
  hb[idx] = f2b(s);
}

// ======================= TIER 2 (precompute xproj + AW) =======================

// transpose-convert W [1024][4096] f32 -> WT [4096][1024] bf16; grid.z picks matrix
__global__ __launch_bounds__(256) void k_tw2(
    const float* __restrict__ Wx, const float* __restrict__ Wh,
    const float* __restrict__ Wa,
    unsigned short* __restrict__ WxT, unsigned short* __restrict__ WhT,
    unsigned short* __restrict__ WaT) {
  __shared__ float tile[64][65];
  int j0 = blockIdx.x * 64;   // 0..4095
  int k0 = blockIdx.y * 64;   // 0..1023
  int z = blockIdx.z;
  const float* src = (z == 0) ? Wx : (z == 1) ? Wh : Wa;
  unsigned short* dst = (z == 0) ? WxT : (z == 1) ? WhT : WaT;
  for (int i = threadIdx.x; i < 4096; i += 256) {
    int r = i >> 6, c = i & 63;     // r: k-offset, c: j-offset (coalesced read)
    tile[r][c] = src[(size_t)(k0 + r) * 4096 + (j0 + c)];
  }
  __syncthreads();
  for (int i = threadIdx.x; i < 4096; i += 256) {
    int r = i >> 6, c = i & 63;     // r: j-offset, c: k-offset (coalesced write)
    dst[(size_t)(j0 + r) * 1024 + (k0 + c)] = f2b(tile[c][r]);
  }
}

// xb2[(t*256+n)][k] = bf16(x[n][t][k]) ; grid 4096 blocks x 256 thr, 4 rows/block
__global__ __launch_bounds__(256) void k_conv_x2(
    const float* __restrict__ x, unsigned short* __restrict__ xb2) {
  int b = blockIdx.x, tid = threadIdx.x;
  #pragma unroll
  for (int rr = 0; rr < 4; ++rr) {
    int r = b * 4 + rr;
    int t = r >> 8, n = r & 255;
    const float4* src = (const float4*)(x + ((size_t)n * 64 + t) * 1024);
    float4 v = src[tid];
    ushort4 o; o.x = f2b(v.x); o.y = f2b(v.y); o.z = f2b(v.z); o.w = f2b(v.w);
    ((ushort4*)(xb2 + (size_t)r * 1024))[tid] = o;
  }
}

// Ab[n][h][p] bf16 (same layout as A), Abt[(p*256+n)][h] bf16 (transposed)
// grid (256 n, 4 h-chunks of 256)
__global__ __launch_bounds__(256) void k_prep_A(
    const float* __restrict__ A, unsigned short* __restrict__ Ab,
    unsigned short* __restrict__ Abt) {
  __shared__ float tile[256][17];
  int n = blockIdx.x;
  int h0 = blockIdx.y * 256;
  int tid = threadIdx.x;
  const float* src = A + (size_t)n * 16384 + (size_t)h0 * 16;
  #pragma unroll
  for (int i = 0; i < 16; ++i) {
    int idx = i * 256 + tid;           // 0..4095
    float v = src[idx];
    Ab[(size_t)n * 16384 + (size_t)h0 * 16 + idx] = f2b(v);
    tile[idx >> 4][idx & 15] = v;
  }
  __syncthreads();
  #pragma unroll
  for (int i = 0; i < 16; ++i) {
    int idx = i * 256 + tid;           // 0..4095
    int p = idx >> 8, h = idx & 255;
    Abt[((size_t)(p * 256 + n)) * 1024 + h0 + h] = f2b(tile[h][p]);
  }
}

// C[M][4096] bf16 = A[M][1024] bf16 @ Bt[4096][1024]^T, 128x128 tile, BK=64, dbuf
__global__ __launch_bounds__(512) void k_gemm(
    const unsigned short* __restrict__ Asrc,
    const unsigned short* __restrict__ Bt,
    unsigned short* __restrict__ C) {
  __shared__ __align__(16) unsigned short smem[36864]; // 2 x (A 128x72 + B 128x72)
  int tid = threadIdx.x;
  int bx = blockIdx.x, by = blockIdx.y;
  int lane = tid & 63, wave = tid >> 6;
  int wr = wave >> 1;   // 0..3: 32-row group
  int wc = wave & 1;    // 0..1: 64-col group
  int srow = tid >> 3;  // 0..63
  int scol = (tid & 7) * 8;
  const unsigned short* arow0 = Asrc + ((size_t)(bx * 128 + srow)) * 1024 + scol;
  const unsigned short* arow1 = arow0 + (size_t)64 * 1024;
  const unsigned short* brow0 = Bt + ((size_t)(by * 128 + srow)) * 1024 + scol;
  const unsigned short* brow1 = brow0 + (size_t)64 * 1024;

  f32x4 acc[2][4];
  #pragma unroll
  for (int m = 0; m < 2; ++m)
    #pragma unroll
    for (int nn = 0; nn < 4; ++nn) acc[m][nn] = {0.f, 0.f, 0.f, 0.f};

  uint4 ra0, ra1, rb0, rb1;
  auto gload = [&](int kt) {
    int k0 = kt * 64;
    ra0 = *(const uint4*)(arow0 + k0);
    ra1 = *(const uint4*)(arow1 + k0);
    rb0 = *(const uint4*)(brow0 + k0);
    rb1 = *(const uint4*)(brow1 + k0);
  };
  int frow = lane & 15, fk = (lane >> 4) * 8;
  gload(0);
  int cur = 0;
  for (int kt = 0; kt < 16; ++kt) {
    unsigned short* As = smem + cur * 18432;
    unsigned short* Bs = As + 9216;
    *(uint4*)(As + srow * 72 + scol) = ra0;
    *(uint4*)(As + (srow + 64) * 72 + scol) = ra1;
    *(uint4*)(Bs + srow * 72 + scol) = rb0;
    *(uint4*)(Bs + (srow + 64) * 72 + scol) = rb1;
    __syncthreads();
    if (kt + 1 < 16) gload(kt + 1);
    #pragma unroll
    for (int kk = 0; kk < 2; ++kk) {
      bh8 af[2], bf[4];
      #pragma unroll
      for (int m = 0; m < 2; ++m)
        af[m] = *(const bh8*)(As + (wr * 32 + m * 16 + frow) * 72 + kk * 32 + fk);
      #pragma unroll
      for (int nn = 0; nn < 4; ++nn)
        bf[nn] = *(const bh8*)(Bs + (wc * 64 + nn * 16 + frow) * 72 + kk * 32 + fk);
      #pragma unroll
      for (int m = 0; m < 2; ++m)
        #pragma unroll
        for (int nn = 0; nn < 4; ++nn)
          acc[m][nn] = __builtin_amdgcn_mfma_f32_16x16x32_bf16(af[m], bf[nn], acc[m][nn], 0, 0, 0);
    }
    cur ^= 1;
  }
  int rbase = bx * 128 + wr * 32 + (lane >> 4) * 4;
  int cbase = by * 128 + wc * 64 + frow;
  #pragma unroll
  for (int m = 0; m < 2; ++m)
    #pragma unroll
    for (int nn = 0; nn < 4; ++nn)
      #pragma unroll
      for (int reg = 0; reg < 4; ++reg)
        C[(size_t)(rbase + m * 16 + reg) * 4096 + (cbase + nn * 16)] = f2b(acc[m][nn][reg]);
}

// per step: scores + softmax + apre[n][j] = sum_p w_p * AW2[(p*256+n)][j]
__global__ __launch_bounds__(256) void k_attn2(
    const unsigned short* __restrict__ Ab,   // [256][1024][16]
    const unsigned short* __restrict__ AW2,  // [(p*256+n)][4096]
    const unsigned short* __restrict__ hb,   // [256][1024]
    float* __restrict__ apre) {              // [256][4096]
  int n = blockIdx.x, tid = threadIdx.x;
  int lane = tid & 63, wave = tid >> 6;
  ushort4 hv4 = *(const ushort4*)(hb + (size_t)n * 1024 + tid * 4);
  float hv[4] = {b2f(hv4.x), b2f(hv4.y), b2f(hv4.z), b2f(hv4.w)};
  float s[16];
  #pragma unroll
  for (int p = 0; p < 16; ++p) s[p] = 0.f;
  const unsigned short* arow = Ab + (size_t)n * 16384 + tid * 64;
  #pragma unroll
  for (int u = 0; u < 4; ++u) {
    bh8 a0 = *(const bh8*)(arow + u * 16);
    bh8 a1 = *(const bh8*)(arow + u * 16 + 8);
    #pragma unroll
    for (int p = 0; p < 8; ++p) s[p] += hv[u] * b2f((unsigned short)a0[p]);
    #pragma unroll
    for (int p = 0; p < 8; ++p) s[8 + p] += hv[u] * b2f((unsigned short)a1[p]);
  }
  #pragma unroll
  for (int p = 0; p < 16; ++p) {
    float v = s[p];
    #pragma unroll
    for (int off = 32; off > 0; off >>= 1) v += __shfl_xor(v, off);
    s[p] = v;
  }
  __shared__ float red[4][16];
  __shared__ float sc_sh[16];
  if (lane == 0) {
    #pragma unroll
    for (int p = 0; p < 16; ++p) red[wave][p] = s[p];
  }
  __syncthreads();
  if (tid < 16)
    sc_sh[tid] = (red[0][tid] + red[1][tid] + red[2][tid] + red[3][tid]) * 0.03125f;
  __syncthreads();
  float sc[16];
  #pragma unroll
  for (int p = 0; p < 16; ++p) sc[p] = sc_sh[p];
  float m = sc[0];
  #pragma unroll
  for (int p = 1; p < 16; ++p) m = fmaxf(m, sc[p]);
  float w[16]; float sum = 0.f;
  #pragma unroll
  for (int p = 0; p < 16; ++p) { w[p] = __expf(sc[p] - m); sum += w[p]; }
  float inv = 1.0f / sum;
  #pragma unroll
  for (int p = 0; p < 16; ++p) w[p] *= inv;
  // apre: 16 consecutive j per thread (two bh8 chunks), 16 coalesced p-streams
  #pragma unroll
  for (int i = 0; i < 2; ++i) {
    int j = tid * 16 + i * 8;
    float a8[8];
    #pragma unroll
    for (int u = 0; u < 8; ++u) a8[u] = 0.f;
    #pragma unroll
    for (int p = 0; p < 16; ++p) {
      bh8 v = *(const bh8*)(AW2 + ((size_t)(p * 256 + n)) * 4096 + j);
      #pragma unroll
      for (int u = 0; u < 8; ++u) a8[u] += w[p] * b2f((unsigned short)v[u]);
    }
    float4* dst = (float4*)(apre + (size_t)n * 4096 + j);
    dst[0] = make_float4(a8[0], a8[1], a8[2], a8[3]);
    dst[1] = make_float4(a8[4], a8[5], a8[6], a8[7]);
  }
}

// per step: a = h@WhT (MFMA) + xproj[t] + apre + b ; fused cell update
__global__ __launch_bounds__(512) void k_step2(
    const unsigned short* __restrict__ WhT,    // [4096][1024]
    const unsigned short* __restrict__ hr,     // [256][1024]
    const unsigned short* __restrict__ xproj,  // [(t*256+n)][4096]
    const float* __restrict__ apre,            // [256][4096]
    const float* __restrict__ bias,
    unsigned short* __restrict__ hw,
    float* __restrict__ cst,
    float* __restrict__ out,
    int t) {
  __shared__ __align__(16) unsigned short smem[18432];
  int tid = threadIdx.x;
  int bn = blockIdx.x;   // 64 col tiles: 16 hcols x 4 quadrants
  int bm = blockIdx.y;   // 4 batch tiles of 64
  int lane = tid & 63, wave = tid >> 6;
  int wr = wave >> 1, wc = wave & 1;
  int nbase = bm * 64, j0 = bn * 16;
  int srow = tid >> 3, scol = (tid & 7) * 8;
  int bj = ((srow >> 4) * 1024) + j0 + (srow & 15);
  const unsigned short* asrc = hr + (size_t)(nbase + srow) * 1024 + scol;
  const unsigned short* bsrc = WhT + (size_t)bj * 1024 + scol;

  f32x4 acc0 = {0.f, 0.f, 0.f, 0.f};
  f32x4 acc1 = {0.f, 0.f, 0.f, 0.f};
  uint4 ra, rb;
  auto gload = [&](int kt) {
    ra = *(const uint4*)(asrc + kt * 64);
    rb = *(const uint4*)(bsrc + kt * 64);
  };
  int frow = lane & 15, fk = (lane >> 4) * 8;
  gload(0);
  int cur = 0;
  for (int kt = 0; kt < 16; ++kt) {
    unsigned short* As = smem + cur * 4608;
    unsigned short* Bs = smem + 9216 + cur * 4608;
    *(uint4*)(As + srow * 72 + scol) = ra;
    *(uint4*)(Bs + srow * 72 + scol) = rb;
    __syncthreads();
    if (kt + 1 < 16) gload(kt + 1);
    #pragma unroll
    for (int kk = 0; kk < 2; ++kk) {
      bh8 af = *(const bh8*)(As + (wr * 16 + frow) * 72 + kk * 32 + fk);
      bh8 b0 = *(const bh8*)(Bs + (wc * 32 + frow) * 72 + kk * 32 + fk);
      bh8 b1 = *(const bh8*)(Bs + (wc * 32 + 16 + frow) * 72 + kk * 32 + fk);
      acc0 = __builtin_amdgcn_mfma_f32_16x16x32_bf16(af, b0, acc0, 0, 0, 0);
      acc1 = __builtin_amdgcn_mfma_f32_16x16x32_bf16(af, b1, acc1, 0, 0, 0);
    }
    cur ^= 1;
  }
  __syncthreads();
  float* a_lds = (float*)smem;   // [64][65] f32
  {
    int r0 = wr * 16 + (lane >> 4) * 4;
    int c0 = wc * 32 + frow;
    #pragma unroll
    for (int reg = 0; reg < 4; ++reg) {
      a_lds[(r0 + reg) * 65 + c0]      = acc0[reg];
      a_lds[(r0 + reg) * 65 + c0 + 16] = acc1[reg];
    }
  }
  __syncthreads();
  #pragma unroll
  for (int r = 0; r < 2; ++r) {
    int it = r * 512 + tid;
    int row = it >> 4, gl = it & 15;
    int n = nbase + row;
    int g = j0 + gl;
    const unsigned short* xp = xproj + ((size_t)(t * 256 + n)) * 4096 + g;
    const float* ap = apre + (size_t)n * 4096 + g;
    float pre[4];
    #pragma unroll
    for (int q = 0; q < 4; ++q)
      pre[q] = a_lds[row * 65 + q * 16 + gl] + b2f(xp[q * 1024]) + ap[q * 1024] + bias[q * 1024 + g];
    size_t ci = (size_t)n * 1024 + g;
    float cold = cst[ci];
    float si = 1.0f / (1.0f + __expf(-pre[0]));
    float sf = 1.0f / (1.0f + __expf(-pre[1]));
    float so = 1.0f / (1.0f + __expf(-pre[2]));
    float tg = 2.0f / (1.0f + __expf(-2.0f * pre[3])) - 1.0f;
    float cn = sf * cold + si * tg;
    float hn = so * (2.0f / (1.0f + __expf(-2.0f * cn)) - 1.0f);
    cst[ci] = cn;
    out[((size_t)n * T_S + t) * 1024 + g] = hn;
    hw[ci] = f2b(hn);
  }
}

// ======================= TIER 0 (round-1 fallback) =======================

__global__ __launch_bounds__(256) void k_prep_w(
    const float* __restrict__ Wx, const float* __restrict__ Wh,
    const float* __restrict__ Wa, unsigned short* __restrict__ WT) {
  __shared__ float tile[64][65];
  int j0 = blockIdx.x * 64;
  int k0 = blockIdx.y * 64;
  const float* src; int kk0;
  if (k0 < 1024)      { src = Wx; kk0 = k0; }
  else if (k0 < 2048) { src = Wh; kk0 = k0 - 1024; }
  else                { src = Wa; kk0 = k0 - 2048; }
  for (int i = threadIdx.x; i < 4096; i += 256) {
    int r = i >> 6, c = i & 63;
    tile[r][c] = src[(size_t)(kk0 + r) * 4096 + (j0 + c)];
  }
  __syncthreads();
  for (int i = threadIdx.x; i < 4096; i += 256) {
    int r = i >> 6, c = i & 63;
    WT[(size_t)(j0 + r) * 3072 + (k0 + c)] = f2b(tile[c][r]);
  }
}

__global__ void k_conv_x(const float* __restrict__ x, unsigned short* __restrict__ xb) {
  int i = blockIdx.x * blockDim.x + threadIdx.x;
  int stride = gridDim.x * blockDim.x;
  for (; i < 4194304; i += stride) {
    float4 v = ((const float4*)x)[i];
    ushort4 o;
    o.x = f2b(v.x); o.y = f2b(v.y); o.z = f2b(v.z); o.w = f2b(v.w);
    ((ushort4*)xb)[i] = o;
  }
}

__global__ __launch_bounds__(256) void k_attn(
    const float* __restrict__ A, const unsigned short* __restrict__ hb,
    unsigned short* __restrict__ attnb) {
  int n = blockIdx.x;
  int tid = threadIdx.x;
  int lane = tid & 63, wave = tid >> 6;
  float areg[4][16];
  float s[16];
  #pragma unroll
  for (int p = 0; p < 16; ++p) s[p] = 0.f;
  #pragma unroll
  for (int r = 0; r < 4; ++r) {
    int h = r * 256 + tid;
    size_t base = (size_t)n * 1024 + h;
    const float4* a4 = (const float4*)(A + base * 16);
    #pragma unroll
    for (int q = 0; q < 4; ++q) {
      float4 v = a4[q];
      areg[r][q*4+0] = v.x; areg[r][q*4+1] = v.y;
      areg[r][q*4+2] = v.z; areg[r][q*4+3] = v.w;
    }
    float hv = b2f(hb[base]);
    #pragma unroll
    for (int p = 0; p < 16; ++p) s[p] += hv * areg[r][p];
  }
  #pragma unroll
  for (int p = 0; p < 16; ++p) {
    float v = s[p];
    #pragma unroll
    for (int off = 32; off > 0; off >>= 1) v += __shfl_xor(v, off);
    s[p] = v;
  }
  __shared__ float red[4][16];
  __shared__ float sc_sh[16];
  if (lane == 0) {
    #pragma unroll
    for (int p = 0; p < 16; ++p) red[wave][p] = s[p];
  }
  __syncthreads();
  if (tid < 16) {
    sc_sh[tid] = (red[0][tid] + red[1][tid] + red[2][tid] + red[3][tid]) * 0.03125f;
  }
  __syncthreads();
  float sc[16];
  #pragma unroll
  for (int p = 0; p < 16; ++p) sc[p] = sc_sh[p];
  float m = sc[0];
  #pragma unroll
  for (int p = 1; p < 16; ++p) m = fmaxf(m, sc[p]);
  float e[16]; float sum = 0.f;
  #pragma unroll
  for (int p = 0; p < 16; ++p) { e[p] = __expf(sc[p] - m); sum += e[p]; }
  float inv = 1.0f / sum;
  #pragma unroll
  for (int r = 0; r < 4; ++r) {
    float a = 0.f;
    #pragma unroll
    for (int p = 0; p < 16; ++p) a += areg[r][p] * e[p];
    attnb[(size_t)n * 1024 + r * 256 + tid] = f2b(a * inv);
  }
}

__global__ __launch_bounds__(512) void k_step(
    const unsigned short* __restrict__ xb,
    const unsigned short* __restrict__ WT,
    const float* __restrict__ bias,
    const unsigned short* __restrict__ hr,
    const unsigned short* __restrict__ atb,
    unsigned short* __restrict__ hw,
    float* __restrict__ cst,
    float* __restrict__ out,
    int t)
{
  __shared__ __align__(16) unsigned short smem[18432];
  int tid = threadIdx.x;
  int bn = blockIdx.x;
  int bm = blockIdx.y;
  int lane = tid & 63;
  int wave = tid >> 6;
  int wr = wave >> 1;
  int wc = wave & 1;
  int nbase = bm * 64;
  int j0 = bn * 16;
  int srow = tid >> 3;
  int scol = (tid & 7) * 8;
  int bj = ((srow >> 4) * 1024) + j0 + (srow & 15);
  const unsigned short* bsrc = WT + (size_t)bj * 3072 + scol;
  f32x4 acc0 = {0.f, 0.f, 0.f, 0.f};
  f32x4 acc1 = {0.f, 0.f, 0.f, 0.f};
  uint4 ra, rb;
  auto gload = [&](int kt) {
    int k0 = kt * 64;
    const unsigned short* src; size_t rs; int kloc;
    if (k0 < 1024)      { src = xb + (size_t)t * 1024; rs = (size_t)T_S * 1024; kloc = k0; }
    else if (k0 < 2048) { src = hr;  rs = 1024; kloc = k0 - 1024; }
    else                { src = atb; rs = 1024; kloc = k0 - 2048; }
    ra = *(const uint4*)(src + (size_t)(nbase + srow) * rs + kloc + scol);
    rb = *(const uint4*)(bsrc + k0);
  };
  int frow = lane & 15;
  int fk = (lane >> 4) * 8;
  gload(0);
  int cur = 0;
  for (int kt = 0; kt < 48; ++kt) {
    unsigned short* As = smem + cur * 4608;
    unsigned short* Bs = smem + 9216 + cur * 4608;
    *(uint4*)(As + srow * 72 + scol) = ra;
    *(uint4*)(Bs + srow * 72 + scol) = rb;
    __syncthreads();
    if (kt + 1 < 48) gload(kt + 1);
    #pragma unroll
    for (int kk = 0; kk < 2; ++kk) {
      bh8 af  = *(const bh8*)(As + (wr * 16 + frow) * 72 + kk * 32 + fk);
      bh8 bf0 = *(const bh8*)(Bs + (wc * 32 + frow) * 72 + kk * 32 + fk);
      bh8 bf1 = *(const bh8*)(Bs + (wc * 32 + 16 + frow) * 72 + kk * 32 + fk);
      acc0 = __builtin_amdgcn_mfma_f32_16x16x32_bf16(af, bf0, acc0, 0, 0, 0);
      acc1 = __builtin_amdgcn_mfma_f32_16x16x32_bf16(af, bf1, acc1, 0, 0, 0);
    }
    cur ^= 1;
  }
  __syncthreads();
  float* a_lds = (float*)smem;
  {
    int r0 = wr * 16 + (lane >> 4) * 4;
    int c0 = wc * 32 + frow;
    #pragma unroll
    for (int reg = 0; reg < 4; ++reg) {
      a_lds[(r0 + reg) * 65 + c0]      = acc0[reg];
      a_lds[(r0 + reg) * 65 + c0 + 16] = acc1[reg];
    }
  }
  __syncthreads();
  #pragma unroll
  for (int r = 0; r < 2; ++r) {
    int pi = r * 512 + tid;
    int row = pi >> 4, gl = pi & 15;
    int n = nbase + row;
    int g = j0 + gl;
    float ii = a_lds[row * 65 + gl]      + bias[g];
    float ff = a_lds[row * 65 + 16 + gl] + bias[1024 + g];
    float oo = a_lds[row * 65 + 32 + gl] + bias[2048 + g];
    float gg = a_lds[row * 65 + 48 + gl] + bias[3072 + g];
    size_t ci = (size_t)n * 1024 + g;
    float cold = cst[ci];
    float si = 1.0f / (1.0f + __expf(-ii));
    float sf = 1.0f / (1.0f + __expf(-ff));
    float so = 1.0f / (1.0f + __expf(-oo));
    float tg = 2.0f / (1.0f + __expf(-2.0f * gg)) - 1.0f;
    float cn = sf * cold + si * tg;
    float hn = so * (2.0f / (1.0f + __expf(-2.0f * cn)) - 1.0f);
    cst[ci] = cn;
    out[((size_t)n * T_S + t) * 1024 + g] = hn;
    hw[ci] = f2b(hn);
  }
}

// ======================= host =======================

extern "C" void kernel_launch(void* const* d_in, const int* in_sizes, int n_in,
                              void* d_out, int out_size, void* d_ws, size_t ws_size,
                              hipStream_t stream) {
  const float* x  = (const float*)d_in[0];
  const float* A  = (const float*)d_in[1];
  const float* Wx = (const float*)d_in[2];
  const float* Wh = (const float*)d_in[3];
  const float* Wa = (const float*)d_in[4];
  const float* b  = (const float*)d_in[5];
  float* out = (float*)d_out;
  char* ws = (char*)d_ws;

  if (ws_size >= 249561088ull) {
    // ---- Tier 2: precompute xproj + AW ----
    unsigned short* WxT   = (unsigned short*)(ws);              //   8,388,608
    unsigned short* WhT   = (unsigned short*)(ws + 8388608);    //   8,388,608
    unsigned short* WaT   = (unsigned short*)(ws + 16777216);   //   8,388,608
    unsigned short* xb2   = (unsigned short*)(ws + 25165824);   //  33,554,432
    unsigned short* Ab    = (unsigned short*)(ws + 58720256);   //   8,388,608
    unsigned short* Abt   = (unsigned short*)(ws + 67108864);   //   8,388,608
    unsigned short* xproj = (unsigned short*)(ws + 75497472);   // 134,217,728
    unsigned short* AW2   = (unsigned short*)(ws + 209715200);  //  33,554,432
    unsigned short* hA    = (unsigned short*)(ws + 243269632);  //     524,288
    unsigned short* hB    = (unsigned short*)(ws + 243793920);  //     524,288
    float* cst            = (float*)(ws + 244318208);           //   1,048,576
    float* apre           = (float*)(ws + 245366784);           //   4,194,304

    k_tw2<<<dim3(64, 16, 3), 256, 0, stream>>>(Wx, Wh, Wa, WxT, WhT, WaT);
    k_conv_x2<<<4096, 256, 0, stream>>>(x, xb2);
    k_prep_A<<<dim3(256, 4), 256, 0, stream>>>(A, Ab, Abt);
    k_init<<<1024, 256, 0, stream>>>(A, hA, cst);
    k_gemm<<<dim3(128, 32), 512, 0, stream>>>(xb2, WxT, xproj);  // xproj
    k_gemm<<<dim3(32, 32), 512, 0, stream>>>(Abt, WaT, AW2);     // AW
    for (int t = 0; t < 64; ++t) {
      const unsigned short* hr = (t & 1) ? hB : hA;
      unsigned short* hwv      = (t & 1) ? hA : hB;
      k_attn2<<<256, 256, 0, stream>>>(Ab, AW2, hr, apre);
      k_step2<<<dim3(64, 4), 512, 0, stream>>>(WhT, hr, xproj, apre, b, hwv, cst, out, t);
    }
  } else if (ws_size >= 61341696ull) {
    // ---- Tier 0: round-1 fallback ----
    unsigned short* WT  = (unsigned short*)(ws);
    unsigned short* xb  = (unsigned short*)(ws + 25165824);
    unsigned short* hA  = (unsigned short*)(ws + 58720256);
    unsigned short* hB  = (unsigned short*)(ws + 59244544);
    unsigned short* atb = (unsigned short*)(ws + 59768832);
    float* cst          = (float*)(ws + 60293120);

    k_prep_w<<<dim3(64, 48), 256, 0, stream>>>(Wx, Wh, Wa, WT);
    k_conv_x<<<2048, 256, 0, stream>>>(x, xb);
    k_init<<<1024, 256, 0, stream>>>(A, hA, cst);
    for (int t = 0; t < 64; ++t) {
      const unsigned short* hr = (t & 1) ? hB : hA;
      unsigned short* hwv      = (t & 1) ? hA : hB;
      k_attn<<<256, 256, 0, stream>>>(A, hr, atb);
      k_step<<<dim3(64, 4), 512, 0, stream>>>(xb, WT, b, hr, atb, hwv, cst, out, t);
    }
  }
}